// Round 1
// baseline (384.186 us; speedup 1.0000x reference)
//
#include <hip/hip_runtime.h>

typedef __attribute__((ext_vector_type(8))) short bf16x8;
typedef __attribute__((ext_vector_type(4))) float f32x4;

#define Hh   16
#define Ll   680
#define Cc   1024
#define Bb   16
#define NSEG 10

__device__ __forceinline__ unsigned short f32_bf16(float f) {
  union { float f; unsigned int u; } x; x.f = f;
  unsigned int r = x.u + 0x7FFFu + ((x.u >> 16) & 1u);   // RNE
  return (unsigned short)(r >> 16);
}
__device__ __forceinline__ float bf16_f32(unsigned short u) {
  union { unsigned int u; float f; } x; x.u = ((unsigned int)u) << 16;
  return x.f;
}

// ---------------- elementwise f32 -> bf16 cast ----------------
__global__ __launch_bounds__(256) void conv_kernel(const float* __restrict__ src,
                                                   unsigned short* __restrict__ dst, int n) {
  int i = (blockIdx.x * 256 + threadIdx.x) * 4;
  if (i + 3 < n) {
    float4 v = *reinterpret_cast<const float4*>(src + i);
    ushort4 o;
    o.x = f32_bf16(v.x); o.y = f32_bf16(v.y); o.z = f32_bf16(v.z); o.w = f32_bf16(v.w);
    *reinterpret_cast<ushort4*>(dst + i) = o;
  }
}

// bias = concat(q_bias, zeros, v_bias)
__global__ __launch_bounds__(256) void bias_kernel(const float* __restrict__ qb,
                                                   const float* __restrict__ vb,
                                                   float* __restrict__ out) {
  int i = blockIdx.x * 256 + threadIdx.x;
  if (i < 3072) {
    float v = 0.f;
    if (i < 1024) v = qb[i];
    else if (i >= 2048) v = vb[i - 2048];
    out[i] = v;
  }
}

// ---------------- B^T GEMM: out[m][n] = sum_k A[m][k]*Bm[n][k] + bias[n] ----------------
// A: M x K bf16 row-major, Bm: N x K bf16 row-major. M%128==0, N%128==0, K%64==0.
// 128x128 block tile, 4 waves, each wave 64x64 (4x4 of 16x16 MFMA).
template <bool OUT_BF16>
__global__ __launch_bounds__(256) void gemm_bt(const unsigned short* __restrict__ A,
                                               const unsigned short* __restrict__ Bm,
                                               const float* __restrict__ bias,
                                               void* __restrict__ outp,
                                               int M, int N, int K) {
  constexpr int LDSP = 88;   // 176B row stride: 16B-aligned, 2-way-only bank aliasing
  __shared__ unsigned short As[128 * LDSP];
  __shared__ unsigned short Bs[128 * LDSP];
  const int t = threadIdx.x;
  const int lane = t & 63, w = t >> 6;
  const int col = lane & 15, quad = lane >> 4;
  const int wm = (w & 1) * 64, wn = (w >> 1) * 64;
  const int m0 = blockIdx.y * 128, n0 = blockIdx.x * 128;

  f32x4 acc[4][4];
#pragma unroll
  for (int i = 0; i < 4; ++i)
#pragma unroll
    for (int j = 0; j < 4; ++j)
#pragma unroll
      for (int r = 0; r < 4; ++r) acc[i][j][r] = 0.f;

  for (int k0 = 0; k0 < K; k0 += 64) {
    __syncthreads();
#pragma unroll
    for (int i = 0; i < 4; ++i) {          // stage 128x64 bf16 tiles (1024 chunks of 16B each)
      int c = t + i * 256;
      int r = c >> 3, part = c & 7;
      uint4 va = *reinterpret_cast<const uint4*>(A + (size_t)(m0 + r) * K + k0 + part * 8);
      *reinterpret_cast<uint4*>(&As[r * LDSP + part * 8]) = va;
      uint4 vb = *reinterpret_cast<const uint4*>(Bm + (size_t)(n0 + r) * K + k0 + part * 8);
      *reinterpret_cast<uint4*>(&Bs[r * LDSP + part * 8]) = vb;
    }
    __syncthreads();
#pragma unroll
    for (int kk = 0; kk < 64; kk += 32) {
      bf16x8 af[4], bfr[4];
#pragma unroll
      for (int mi = 0; mi < 4; ++mi)
        af[mi] = *reinterpret_cast<const bf16x8*>(&As[(wm + mi * 16 + col) * LDSP + kk + quad * 8]);
#pragma unroll
      for (int ni = 0; ni < 4; ++ni)
        bfr[ni] = *reinterpret_cast<const bf16x8*>(&Bs[(wn + ni * 16 + col) * LDSP + kk + quad * 8]);
#pragma unroll
      for (int mi = 0; mi < 4; ++mi)
#pragma unroll
        for (int ni = 0; ni < 4; ++ni)
          acc[mi][ni] = __builtin_amdgcn_mfma_f32_16x16x32_bf16(af[mi], bfr[ni], acc[mi][ni], 0, 0, 0);
    }
  }
  // epilogue: C/D layout col=lane&15, row=quad*4+r  (m89/m91-verified)
#pragma unroll
  for (int mi = 0; mi < 4; ++mi) {
#pragma unroll
    for (int ni = 0; ni < 4; ++ni) {
      int gn = n0 + wn + ni * 16 + col;
      float bv = bias[gn];
#pragma unroll
      for (int r = 0; r < 4; ++r) {
        int gm = m0 + wm + mi * 16 + quad * 4 + r;
        float v = acc[mi][ni][r] + bv;
        size_t off = (size_t)gm * N + gn;
        if (OUT_BF16) ((unsigned short*)outp)[off] = f32_bf16(v);
        else ((float*)outp)[off] = v;
      }
    }
  }
}

// ---------------- l2norm + scale, layout (B,L,3,H,D) -> 3x (B,H,L,D) ----------------
__global__ __launch_bounds__(256) void norm_kernel(const unsigned short* __restrict__ qkv,
                                                   const float* __restrict__ slog,
                                                   unsigned short* __restrict__ qt,
                                                   unsigned short* __restrict__ kt,
                                                   unsigned short* __restrict__ vt) {
  int row = blockIdx.x * 256 + threadIdx.x;  // row = bl*16 + h, 174080 total
  int h = row & (Hh - 1);
  int bl = row >> 4;
  int b = bl / Ll, l = bl % Ll;
  const unsigned short* src = qkv + (size_t)bl * 3072 + h * 64;
  size_t dsto = ((size_t)(b * Hh + h) * Ll + l) * 64;
  float smul = __expf(fminf(slog[h], 4.6051701859880914f));  // min(scale_log, log(100))

  uint4 blk[8];
  unsigned short tmp[8];
  // q: l2norm * smul
#pragma unroll
  for (int i = 0; i < 8; ++i) blk[i] = *reinterpret_cast<const uint4*>(src + i * 8);
  float ss = 0.f;
#pragma unroll
  for (int i = 0; i < 8; ++i) {
    const unsigned short* u = (const unsigned short*)&blk[i];
#pragma unroll
    for (int e = 0; e < 8; ++e) { float f = bf16_f32(u[e]); ss += f * f; }
  }
  float sc = smul / fmaxf(sqrtf(ss), 1e-12f);
#pragma unroll
  for (int i = 0; i < 8; ++i) {
    const unsigned short* u = (const unsigned short*)&blk[i];
#pragma unroll
    for (int e = 0; e < 8; ++e) tmp[e] = f32_bf16(bf16_f32(u[e]) * sc);
    *reinterpret_cast<uint4*>(qt + dsto + i * 8) = *reinterpret_cast<uint4*>(tmp);
  }
  // k: l2norm
#pragma unroll
  for (int i = 0; i < 8; ++i) blk[i] = *reinterpret_cast<const uint4*>(src + 1024 + i * 8);
  ss = 0.f;
#pragma unroll
  for (int i = 0; i < 8; ++i) {
    const unsigned short* u = (const unsigned short*)&blk[i];
#pragma unroll
    for (int e = 0; e < 8; ++e) { float f = bf16_f32(u[e]); ss += f * f; }
  }
  sc = 1.f / fmaxf(sqrtf(ss), 1e-12f);
#pragma unroll
  for (int i = 0; i < 8; ++i) {
    const unsigned short* u = (const unsigned short*)&blk[i];
#pragma unroll
    for (int e = 0; e < 8; ++e) tmp[e] = f32_bf16(bf16_f32(u[e]) * sc);
    *reinterpret_cast<uint4*>(kt + dsto + i * 8) = *reinterpret_cast<uint4*>(tmp);
  }
  // v: copy
#pragma unroll
  for (int i = 0; i < 8; ++i)
    *reinterpret_cast<uint4*>(vt + dsto + i * 8) =
        *reinterpret_cast<const uint4*>(src + 2048 + i * 8);
}

// ---------------- segment attention, MFMA + online softmax ----------------
// block = one (b,h,seg). 4 waves; each wave owns one 16-row Q-tile per pass.
// K/V processed in 128-wide chunks; V transposed into LDS; P via LDS (m120 pattern).
__global__ __launch_bounds__(256) void attn_kernel(const unsigned short* __restrict__ qg,
                                                   const unsigned short* __restrict__ kg,
                                                   const unsigned short* __restrict__ vg,
                                                   const int* __restrict__ pnums,
                                                   unsigned short* __restrict__ outb) {
  __shared__ unsigned short Ks[128 * 88];     // [j][d] stride 88
  __shared__ unsigned short Vt[64 * 136];     // [d][j] stride 136
  __shared__ unsigned short Ps[4 * 16 * 136]; // per-wave [row][j] stride 136

  const int t = threadIdx.x;
  const int lane = t & 63, w = t >> 6;
  const int col = lane & 15, quad = lane >> 4;

  int seg = blockIdx.x % NSEG;
  int bh = blockIdx.x / NSEG;
  int b = bh >> 4, h = bh & 15;
  int ln = pnums[seg];
  int start = 0;
  for (int i = 0; i < seg; ++i) start += pnums[i];

  int LP = (ln + 15) & ~15;
  int nqt = LP >> 4;
  int npass = (nqt + 3) >> 2;
  int nchunk = (ln + 127) >> 7;

  const unsigned short* qb = qg + ((size_t)(b * Hh + h) * Ll + start) * 64;
  const unsigned short* kb = kg + ((size_t)(b * Hh + h) * Ll + start) * 64;
  const unsigned short* vb = vg + ((size_t)(b * Hh + h) * Ll + start) * 64;

  for (int pass = 0; pass < npass; ++pass) {
    int qt = pass * 4 + w;
    bool qvalid = qt < nqt;
    int qi = qt * 16 + col;  // A-operand row (always in-bounds of the (b,h) slab)
    bf16x8 qf0 = *reinterpret_cast<const bf16x8*>(qb + (size_t)qi * 64 + quad * 8);
    bf16x8 qf1 = *reinterpret_cast<const bf16x8*>(qb + (size_t)qi * 64 + 32 + quad * 8);

    f32x4 o[4];
#pragma unroll
    for (int nt = 0; nt < 4; ++nt)
#pragma unroll
      for (int r = 0; r < 4; ++r) o[nt][r] = 0.f;
    float m4[4] = {-1e30f, -1e30f, -1e30f, -1e30f};
    float l4[4] = {0.f, 0.f, 0.f, 0.f};

    for (int ch = 0; ch < nchunk; ++ch) {
      int j0 = ch * 128;
      __syncthreads();
#pragma unroll
      for (int i = 0; i < 4; ++i) {  // stage K chunk + transposed V chunk (zero-padded)
        int c = t + i * 256;
        int r = c >> 3, part = c & 7;
        int j = j0 + r;
        uint4 kv = {0, 0, 0, 0}, vv = {0, 0, 0, 0};
        if (j < ln) {
          kv = *reinterpret_cast<const uint4*>(kb + (size_t)j * 64 + part * 8);
          vv = *reinterpret_cast<const uint4*>(vb + (size_t)j * 64 + part * 8);
        }
        *reinterpret_cast<uint4*>(&Ks[r * 88 + part * 8]) = kv;
        const unsigned short* vs = (const unsigned short*)&vv;
#pragma unroll
        for (int e = 0; e < 8; ++e) Vt[(part * 8 + e) * 136 + r] = vs[e];
      }
      __syncthreads();

      // S = Q K^T for this wave's Q-tile (rows=q, cols=j)
      f32x4 sf[8];
#pragma unroll
      for (int jt = 0; jt < 8; ++jt) {
        const unsigned short* kr = &Ks[(jt * 16 + col) * 88 + quad * 8];
        bf16x8 k0 = *reinterpret_cast<const bf16x8*>(kr);
        bf16x8 k1 = *reinterpret_cast<const bf16x8*>(kr + 32);
        f32x4 s;
#pragma unroll
        for (int r = 0; r < 4; ++r) s[r] = 0.f;
        s = __builtin_amdgcn_mfma_f32_16x16x32_bf16(qf0, k0, s, 0, 0, 0);
        s = __builtin_amdgcn_mfma_f32_16x16x32_bf16(qf1, k1, s, 0, 0, 0);
        if (j0 + jt * 16 + col >= ln) {
#pragma unroll
          for (int r = 0; r < 4; ++r) s[r] = -1e30f;
        }
        sf[jt] = s;
      }
      // online softmax: row stats live on the 16-lane quad group
      float mc[4];
#pragma unroll
      for (int r = 0; r < 4; ++r) mc[r] = sf[0][r];
#pragma unroll
      for (int jt = 1; jt < 8; ++jt)
#pragma unroll
        for (int r = 0; r < 4; ++r) mc[r] = fmaxf(mc[r], sf[jt][r]);
#pragma unroll
      for (int mask = 1; mask <= 8; mask <<= 1)
#pragma unroll
        for (int r = 0; r < 4; ++r) mc[r] = fmaxf(mc[r], __shfl_xor(mc[r], mask));
      float alpha[4];
#pragma unroll
      for (int r = 0; r < 4; ++r) {
        float mn = fmaxf(m4[r], mc[r]);
        alpha[r] = __expf(m4[r] - mn);
        m4[r] = mn;
      }
      float ls[4] = {0.f, 0.f, 0.f, 0.f};
#pragma unroll
      for (int jt = 0; jt < 8; ++jt)
#pragma unroll
        for (int r = 0; r < 4; ++r) {
          float p = __expf(sf[jt][r] - m4[r]);
          ls[r] += p;
          Ps[(w * 16 + quad * 4 + r) * 136 + jt * 16 + col] = f32_bf16(p);
        }
#pragma unroll
      for (int mask = 1; mask <= 8; mask <<= 1)
#pragma unroll
        for (int r = 0; r < 4; ++r) ls[r] += __shfl_xor(ls[r], mask);
#pragma unroll
      for (int r = 0; r < 4; ++r) l4[r] = l4[r] * alpha[r] + ls[r];
#pragma unroll
      for (int nt = 0; nt < 4; ++nt)
#pragma unroll
        for (int r = 0; r < 4; ++r) o[nt][r] *= alpha[r];

      // O += P * V   (A=P from LDS, B=Vt contiguous)
#pragma unroll
      for (int kk = 0; kk < 4; ++kk) {
        bf16x8 pf = *reinterpret_cast<const bf16x8*>(&Ps[(w * 16 + col) * 136 + kk * 32 + quad * 8]);
#pragma unroll
        for (int nt = 0; nt < 4; ++nt) {
          bf16x8 vf = *reinterpret_cast<const bf16x8*>(&Vt[(nt * 16 + col) * 136 + kk * 32 + quad * 8]);
          o[nt] = __builtin_amdgcn_mfma_f32_16x16x32_bf16(pf, vf, o[nt], 0, 0, 0);
        }
      }
    }
    if (qvalid) {
      float inv[4];
#pragma unroll
      for (int r = 0; r < 4; ++r) inv[r] = 1.f / l4[r];
#pragma unroll
      for (int nt = 0; nt < 4; ++nt)
#pragma unroll
        for (int r = 0; r < 4; ++r) {
          int ri = qt * 16 + quad * 4 + r;
          if (ri < ln) {
            size_t off = ((size_t)b * Ll + start + ri) * Cc + h * 64 + nt * 16 + col;
            outb[off] = f32_bf16(o[nt][r] * inv[r]);
          }
        }
    }
  }
}

extern "C" void kernel_launch(void* const* d_in, const int* in_sizes, int n_in,
                              void* d_out, int out_size, void* d_ws, size_t ws_size,
                              hipStream_t stream) {
  const float* x     = (const float*)d_in[0];
  const int*   pn    = (const int*)d_in[1];
  const float* wqkv  = (const float*)d_in[2];
  const float* qbias = (const float*)d_in[3];
  const float* vbias = (const float*)d_in[4];
  const float* slog  = (const float*)d_in[5];
  const float* wproj = (const float*)d_in[6];
  const float* pbias = (const float*)d_in[7];
  float* out = (float*)d_out;

  const size_t nX   = (size_t)Bb * Ll * Cc;      // 11,141,120
  const size_t nWq  = (size_t)3 * Cc * Cc;       // 3,145,728
  const size_t nWp  = (size_t)Cc * Cc;           // 1,048,576
  const size_t nQKV = (size_t)Bb * Ll * 3 * Cc;  // 33,423,360

  char* p = (char*)d_ws;
  unsigned short* xb     = (unsigned short*)p;  p += nX * 2;
  unsigned short* wqkvb  = (unsigned short*)p;  p += nWq * 2;
  unsigned short* wprojb = (unsigned short*)p;  p += nWp * 2;
  float*          bqkv   = (float*)p;           p += 3072 * 4;
  unsigned short* qkv    = (unsigned short*)p;  p += nQKV * 2;
  unsigned short* qt     = (unsigned short*)p;  p += nX * 2;
  unsigned short* kt     = (unsigned short*)p;  p += nX * 2;
  unsigned short* vt     = (unsigned short*)p;  p += nX * 2;
  unsigned short* attn   = xb;  // reuse: xb dead after QKV GEMM

  conv_kernel<<<(int)(nX / 1024), 256, 0, stream>>>(x, xb, (int)nX);
  conv_kernel<<<(int)(nWq / 1024), 256, 0, stream>>>(wqkv, wqkvb, (int)nWq);
  conv_kernel<<<(int)(nWp / 1024), 256, 0, stream>>>(wproj, wprojb, (int)nWp);
  bias_kernel<<<12, 256, 0, stream>>>(qbias, vbias, bqkv);

  gemm_bt<true><<<dim3(24, 85), 256, 0, stream>>>(xb, wqkvb, bqkv, qkv, 10880, 3072, 1024);
  norm_kernel<<<680, 256, 0, stream>>>(qkv, slog, qt, kt, vt);
  attn_kernel<<<Bb * Hh * NSEG, 256, 0, stream>>>(qt, kt, vt, pn, attn);
  gemm_bt<false><<<dim3(8, 85), 256, 0, stream>>>(attn, wprojb, pbias, out, 10880, 1024, 1024);
}

// Round 2
// 343.841 us; speedup vs baseline: 1.1173x; 1.1173x over previous
//
#include <hip/hip_runtime.h>

typedef __attribute__((ext_vector_type(8))) short bf16x8;
typedef __attribute__((ext_vector_type(4))) float f32x4;

#define Hh   16
#define Ll   680
#define Cc   1024
#define Bb   16
#define NSEG 10

__device__ __forceinline__ unsigned short f32_bf16(float f) {
  union { float f; unsigned int u; } x; x.f = f;
  unsigned int r = x.u + 0x7FFFu + ((x.u >> 16) & 1u);   // RNE
  return (unsigned short)(r >> 16);
}
__device__ __forceinline__ float bf16_f32(unsigned short u) {
  union { unsigned int u; float f; } x; x.u = ((unsigned int)u) << 16;
  return x.f;
}

__device__ __forceinline__ void async_copy16(const unsigned short* g, unsigned short* l) {
  __builtin_amdgcn_global_load_lds(
      (const __attribute__((address_space(1))) unsigned int*)g,
      (__attribute__((address_space(3))) unsigned int*)l, 16, 0, 0);
}

// ---------------- elementwise f32 -> bf16 cast ----------------
__global__ __launch_bounds__(256) void conv_kernel(const float* __restrict__ src,
                                                   unsigned short* __restrict__ dst, int n) {
  int i = (blockIdx.x * 256 + threadIdx.x) * 4;
  if (i + 3 < n) {
    float4 v = *reinterpret_cast<const float4*>(src + i);
    ushort4 o;
    o.x = f32_bf16(v.x); o.y = f32_bf16(v.y); o.z = f32_bf16(v.z); o.w = f32_bf16(v.w);
    *reinterpret_cast<ushort4*>(dst + i) = o;
  }
}

// bias = concat(q_bias, zeros, v_bias)
__global__ __launch_bounds__(256) void bias_kernel(const float* __restrict__ qb,
                                                   const float* __restrict__ vb,
                                                   float* __restrict__ out) {
  int i = blockIdx.x * 256 + threadIdx.x;
  if (i < 3072) {
    float v = 0.f;
    if (i < 1024) v = qb[i];
    else if (i >= 2048) v = vb[i - 2048];
    out[i] = v;
  }
}

// ---------------- B^T GEMM via global_load_lds + XOR-swizzled LDS ----------------
// out[m][n] = sum_k A[m][k]*Bm[n][k] + bias[n]. M%128==0, N%128==0, K%64==0.
// LDS tile 128x64 bf16 stored as 16B chunks: chunk(row,part) at index row*8 + (part ^ (row&7)).
// Staging: wave-uniform LDS base + lane*16 (global_load_lds constraint), coalesced 1KB/wave.
// Fragment ds_read_b128: 16 col-lanes hit (p^(col&7))*4 -> all 32 banks, conflict-free.
template <bool OUT_BF16>
__global__ __launch_bounds__(256) void gemm_bt(const unsigned short* __restrict__ A,
                                               const unsigned short* __restrict__ Bm,
                                               const float* __restrict__ bias,
                                               void* __restrict__ outp,
                                               int M, int N, int K) {
  __shared__ __align__(16) unsigned short As[128 * 64];
  __shared__ __align__(16) unsigned short Bs[128 * 64];
  const int t = threadIdx.x;
  const int lane = t & 63, w = t >> 6;
  const int col = lane & 15, quad = lane >> 4;
  const int wm = (w & 1) * 64, wn = (w >> 1) * 64;
  const int m0 = blockIdx.y * 128, n0 = blockIdx.x * 128;

  f32x4 acc[4][4];
#pragma unroll
  for (int i = 0; i < 4; ++i)
#pragma unroll
    for (int j = 0; j < 4; ++j)
#pragma unroll
      for (int r = 0; r < 4; ++r) acc[i][j][r] = 0.f;

  // per-thread staging chunk: c = w*256 + i*64 + lane
  const int cbase = w * 256 + (t & 63);
  for (int k0 = 0; k0 < K; k0 += 64) {
    __syncthreads();
#pragma unroll
    for (int i = 0; i < 4; ++i) {
      int c = cbase + i * 64;
      int r = c >> 3;
      int part = (c & 7) ^ (r & 7);
      const unsigned short* ga = A + (size_t)(m0 + r) * K + k0 + part * 8;
      const unsigned short* gb = Bm + (size_t)(n0 + r) * K + k0 + part * 8;
      async_copy16(ga, As + (w * 256 + i * 64) * 8);
      async_copy16(gb, Bs + (w * 256 + i * 64) * 8);
    }
    __syncthreads();
#pragma unroll
    for (int kk = 0; kk < 64; kk += 32) {
      const int p = (kk >> 3) + quad;  // k-chunk index
      bf16x8 af[4], bfr[4];
#pragma unroll
      for (int mi = 0; mi < 4; ++mi) {
        int row = wm + mi * 16 + col;
        af[mi] = *reinterpret_cast<const bf16x8*>(&As[(row * 8 + (p ^ (col & 7))) * 8]);
      }
#pragma unroll
      for (int ni = 0; ni < 4; ++ni) {
        int row = wn + ni * 16 + col;
        bfr[ni] = *reinterpret_cast<const bf16x8*>(&Bs[(row * 8 + (p ^ (col & 7))) * 8]);
      }
#pragma unroll
      for (int mi = 0; mi < 4; ++mi)
#pragma unroll
        for (int ni = 0; ni < 4; ++ni)
          acc[mi][ni] = __builtin_amdgcn_mfma_f32_16x16x32_bf16(af[mi], bfr[ni], acc[mi][ni], 0, 0, 0);
    }
  }
  // epilogue: C/D layout col=lane&15, row=quad*4+r  (m89/m91-verified)
#pragma unroll
  for (int mi = 0; mi < 4; ++mi) {
#pragma unroll
    for (int ni = 0; ni < 4; ++ni) {
      int gn = n0 + wn + ni * 16 + col;
      float bv = bias[gn];
#pragma unroll
      for (int r = 0; r < 4; ++r) {
        int gm = m0 + wm + mi * 16 + quad * 4 + r;
        float v = acc[mi][ni][r] + bv;
        size_t off = (size_t)gm * N + gn;
        if (OUT_BF16) ((unsigned short*)outp)[off] = f32_bf16(v);
        else ((float*)outp)[off] = v;
      }
    }
  }
}

// ---------------- fused attention: block = (b,h), segments sequential ----------------
// Per segment: stage normalized K rows + transposed V into LDS once; each pass gives
// 4 waves x one 16-row Q-tile; full-row S in registers -> single-shot softmax -> PV.
// Q l2norm+scale fused in-wave (kills the separate norm kernel + 134MB round trip).
__global__ __launch_bounds__(256) void attn_kernel(const unsigned short* __restrict__ qkv,
                                                   const float* __restrict__ slog,
                                                   const int* __restrict__ pnums,
                                                   unsigned short* __restrict__ outb) {
  __shared__ __align__(16) unsigned short Ks[256 * 72];   // [j][d] stride 72 (bank-rotated)
  __shared__ __align__(16) unsigned short Vt[64 * 264];   // [d][j] stride 264
  __shared__ __align__(16) unsigned short Ps[64 * 264];   // [q_local(w*16+..)][j] stride 264

  const int t = threadIdx.x;
  const int lane = t & 63, w = t >> 6;
  const int col = lane & 15, quad = lane >> 4;
  const int b = blockIdx.x >> 4, h = blockIdx.x & 15;
  const float smul = __expf(fminf(slog[h], 4.6051701859880914f));

  int start = 0;
  for (int seg = 0; seg < NSEG; ++seg) {
    const int ln = pnums[seg];
    const int njt = (ln + 15) >> 4;      // S col tiles (16-wide)
    const int njtp = (njt + 1) & ~1;     // padded to even (32-multiple for PV k-loop)
    const int npass = (njt + 3) >> 2;

    __syncthreads();  // previous segment's LDS reads done
    {  // ---- stage: thread t handles K row t and V row t (normalized K; V transposed) ----
      const int j = t;
      const bool valid = j < ln;
      const unsigned short* krow =
          qkv + ((size_t)(b * Ll + start + (valid ? j : 0)) * 3 + 1) * Cc + h * 64;
      if (valid) {
        uint4 kv[8];
        float ss = 0.f;
#pragma unroll
        for (int i2 = 0; i2 < 8; ++i2) {
          kv[i2] = *reinterpret_cast<const uint4*>(krow + i2 * 8);
          const unsigned short* u = (const unsigned short*)&kv[i2];
#pragma unroll
          for (int e = 0; e < 8; ++e) { float f = bf16_f32(u[e]); ss += f * f; }
        }
        float sc = 1.f / fmaxf(sqrtf(ss), 1e-12f);
#pragma unroll
        for (int i2 = 0; i2 < 8; ++i2) {
          const unsigned short* u = (const unsigned short*)&kv[i2];
          unsigned short tmp[8];
#pragma unroll
          for (int e = 0; e < 8; ++e) tmp[e] = f32_bf16(bf16_f32(u[e]) * sc);
          *reinterpret_cast<uint4*>(&Ks[j * 72 + i2 * 8]) = *reinterpret_cast<uint4*>(tmp);
        }
        const unsigned short* vrow = krow + Cc;  // field 2
#pragma unroll
        for (int i2 = 0; i2 < 8; ++i2) {
          uint4 vv = *reinterpret_cast<const uint4*>(vrow + i2 * 8);
          const unsigned short* u = (const unsigned short*)&vv;
#pragma unroll
          for (int e = 0; e < 8; ++e) Vt[(i2 * 8 + e) * 264 + j] = u[e];  // lane=j: consecutive bytes, conflict-free
        }
      } else {
#pragma unroll
        for (int i2 = 0; i2 < 8; ++i2)
#pragma unroll
          for (int e = 0; e < 8; ++e) Vt[(i2 * 8 + e) * 264 + j] = 0;
      }
    }
    __syncthreads();

    for (int pass = 0; pass < npass; ++pass) {
      const int qt = pass * 4 + w;
      const bool qvalid = qt < njt;
      const int qi = qt * 16 + col;  // always within the (b,h) slab (masked at write)
      const unsigned short* qrow = qkv + ((size_t)(b * Ll + start + qi) * 3) * Cc + h * 64;
      bf16x8 qf0 = *reinterpret_cast<const bf16x8*>(qrow + quad * 8);
      bf16x8 qf1 = *reinterpret_cast<const bf16x8*>(qrow + 32 + quad * 8);
      // row l2norm: 16 elems/lane, reduce across quads
      float ss = 0.f;
#pragma unroll
      for (int e = 0; e < 8; ++e) {
        float f0 = bf16_f32((unsigned short)qf0[e]), f1 = bf16_f32((unsigned short)qf1[e]);
        ss += f0 * f0 + f1 * f1;
      }
      ss += __shfl_xor(ss, 16);
      ss += __shfl_xor(ss, 32);
      const float qsc = smul / fmaxf(sqrtf(ss), 1e-12f);
      bf16x8 qf0s, qf1s;
#pragma unroll
      for (int e = 0; e < 8; ++e) {
        qf0s[e] = (short)f32_bf16(bf16_f32((unsigned short)qf0[e]) * qsc);
        qf1s[e] = (short)f32_bf16(bf16_f32((unsigned short)qf1[e]) * qsc);
      }

      // ---- S = Q K^T across the whole segment (<=16 tiles in registers) ----
      f32x4 sf[16];
#pragma unroll
      for (int jt = 0; jt < 16; ++jt) {
        if (jt >= njtp) continue;
        f32x4 s;
#pragma unroll
        for (int r = 0; r < 4; ++r) s[r] = 0.f;
        if (jt < njt) {
          const unsigned short* kr = &Ks[(jt * 16 + col) * 72 + quad * 8];
          bf16x8 k0 = *reinterpret_cast<const bf16x8*>(kr);
          bf16x8 k1 = *reinterpret_cast<const bf16x8*>(kr + 32);
          s = __builtin_amdgcn_mfma_f32_16x16x32_bf16(qf0s, k0, s, 0, 0, 0);
          s = __builtin_amdgcn_mfma_f32_16x16x32_bf16(qf1s, k1, s, 0, 0, 0);
        }
        if (jt * 16 + col >= ln) {
#pragma unroll
          for (int r = 0; r < 4; ++r) s[r] = -1e30f;
        }
        sf[jt] = s;
      }
      // ---- single-shot softmax (row stats across 16-lane groups) ----
      float m4[4] = {-1e30f, -1e30f, -1e30f, -1e30f};
#pragma unroll
      for (int jt = 0; jt < 16; ++jt) {
        if (jt >= njtp) continue;
#pragma unroll
        for (int r = 0; r < 4; ++r) m4[r] = fmaxf(m4[r], sf[jt][r]);
      }
#pragma unroll
      for (int mask = 1; mask <= 8; mask <<= 1)
#pragma unroll
        for (int r = 0; r < 4; ++r) m4[r] = fmaxf(m4[r], __shfl_xor(m4[r], mask));
      float l4[4] = {0.f, 0.f, 0.f, 0.f};
#pragma unroll
      for (int jt = 0; jt < 16; ++jt) {
        if (jt >= njtp) continue;
#pragma unroll
        for (int r = 0; r < 4; ++r) {
          float pv = __expf(sf[jt][r] - m4[r]);
          l4[r] += pv;
          Ps[(w * 16 + quad * 4 + r) * 264 + jt * 16 + col] = f32_bf16(pv);
        }
      }
#pragma unroll
      for (int mask = 1; mask <= 8; mask <<= 1)
#pragma unroll
        for (int r = 0; r < 4; ++r) l4[r] += __shfl_xor(l4[r], mask);

      // ---- O = P V (A=Ps, B=Vt; per-wave LDS region, no barrier needed) ----
      f32x4 o[4];
#pragma unroll
      for (int nt = 0; nt < 4; ++nt)
#pragma unroll
        for (int r = 0; r < 4; ++r) o[nt][r] = 0.f;
#pragma unroll
      for (int kk2 = 0; kk2 < 8; ++kk2) {
        if (kk2 >= (njtp >> 1)) continue;
        bf16x8 pf = *reinterpret_cast<const bf16x8*>(&Ps[(w * 16 + col) * 264 + kk2 * 32 + quad * 8]);
#pragma unroll
        for (int nt = 0; nt < 4; ++nt) {
          bf16x8 vf = *reinterpret_cast<const bf16x8*>(&Vt[(nt * 16 + col) * 264 + kk2 * 32 + quad * 8]);
          o[nt] = __builtin_amdgcn_mfma_f32_16x16x32_bf16(pf, vf, o[nt], 0, 0, 0);
        }
      }
      if (qvalid) {
        float inv[4];
#pragma unroll
        for (int r = 0; r < 4; ++r) inv[r] = 1.f / l4[r];
#pragma unroll
        for (int nt = 0; nt < 4; ++nt)
#pragma unroll
          for (int r = 0; r < 4; ++r) {
            int ri = qt * 16 + quad * 4 + r;
            if (ri < ln) {
              size_t off = ((size_t)b * Ll + start + ri) * Cc + h * 64 + nt * 16 + col;
              outb[off] = f32_bf16(o[nt][r] * inv[r]);
            }
          }
      }
    }
    start += ln;
  }
}

extern "C" void kernel_launch(void* const* d_in, const int* in_sizes, int n_in,
                              void* d_out, int out_size, void* d_ws, size_t ws_size,
                              hipStream_t stream) {
  const float* x     = (const float*)d_in[0];
  const int*   pn    = (const int*)d_in[1];
  const float* wqkv  = (const float*)d_in[2];
  const float* qbias = (const float*)d_in[3];
  const float* vbias = (const float*)d_in[4];
  const float* slog  = (const float*)d_in[5];
  const float* wproj = (const float*)d_in[6];
  const float* pbias = (const float*)d_in[7];
  float* out = (float*)d_out;

  const size_t nX   = (size_t)Bb * Ll * Cc;      // 11,141,120
  const size_t nWq  = (size_t)3 * Cc * Cc;       // 3,145,728
  const size_t nWp  = (size_t)Cc * Cc;           // 1,048,576
  const size_t nQKV = (size_t)Bb * Ll * 3 * Cc;  // 33,423,360

  char* p = (char*)d_ws;
  unsigned short* xb     = (unsigned short*)p;  p += nX * 2;
  unsigned short* wqkvb  = (unsigned short*)p;  p += nWq * 2;
  unsigned short* wprojb = (unsigned short*)p;  p += nWp * 2;
  float*          bqkv   = (float*)p;           p += 3072 * 4;
  unsigned short* qkv    = (unsigned short*)p;  p += nQKV * 2;
  unsigned short* attn   = xb;  // reuse: xb dead after QKV GEMM

  conv_kernel<<<(int)(nX / 1024), 256, 0, stream>>>(x, xb, (int)nX);
  conv_kernel<<<(int)(nWq / 1024), 256, 0, stream>>>(wqkv, wqkvb, (int)nWq);
  conv_kernel<<<(int)(nWp / 1024), 256, 0, stream>>>(wproj, wprojb, (int)nWp);
  bias_kernel<<<12, 256, 0, stream>>>(qbias, vbias, bqkv);

  gemm_bt<true><<<dim3(24, 85), 256, 0, stream>>>(xb, wqkvb, bqkv, qkv, 10880, 3072, 1024);
  attn_kernel<<<Bb * Hh, 256, 0, stream>>>(qkv, slog, pn, attn);
  gemm_bt<false><<<dim3(8, 85), 256, 0, stream>>>(attn, wprojb, pbias, out, 10880, 1024, 1024);
}